// Round 7
// baseline (1098.178 us; speedup 1.0000x reference)
//
#include <hip/hip_runtime.h>
#include <math.h>

#define D_MODEL 256
#define NHEAD 8
#define HDIM 32
#define NLVL 4
#define NPTS 4
#define DFF 1024
#define NLAYERS 6
#define LEN 3060
#define BS 2
#define MROWS (BS * LEN)   // 6120
#define MPAD 6144
#define PSTRIDE ((size_t)MPAD * 256)

#define REP_MSDA 5         // diagnostic amplification (divide top-5 dur by 5)

typedef __attribute__((ext_vector_type(8))) short bf16x8;
typedef __attribute__((ext_vector_type(4))) float f32x4;

__device__ __forceinline__ unsigned short f2bf(float f) {
    union { float f; unsigned u; } v; v.f = f;
    unsigned r = v.u + 0x7FFF + ((v.u >> 16) & 1);
    return (unsigned short)(r >> 16);
}
__device__ __forceinline__ float bf2f(unsigned short s) {
    union { unsigned u; float f; } v; v.u = ((unsigned)s) << 16;
    return v.f;
}
template <typename T>
__device__ __forceinline__ const T* launder_p(const T* p) {
    unsigned long long a = (unsigned long long)p;
    asm volatile("" : "+v"(a));
    return (const T*)a;
}

#define GLDS(gp, lp) __builtin_amdgcn_global_load_lds(                        \
    (const __attribute__((address_space(1))) void*)(gp),                      \
    (__attribute__((address_space(3))) void*)(lp), 16, 0, 0)

// XCD-bijective block swizzle (nwg % 8 == 0): XCD k gets a contiguous chunk
// of linear block ids -> contiguous row-panels -> A panel lives in one L2.
__device__ __forceinline__ void swz_xy(int& tx, int& ty) {
    const int gx = gridDim.x;
    const int id = blockIdx.y * gx + blockIdx.x;
    const int q  = (gx * gridDim.y) >> 3;
    const int L  = (id & 7) * q + (id >> 3);
    ty = L / gx; tx = L - ty * gx;
}

// ---------------------------------------------------------------------------
__global__ __launch_bounds__(256) void flatten_kernel(
    const float* __restrict__ s0, const float* __restrict__ s1,
    const float* __restrict__ s2, const float* __restrict__ s3,
    const float* __restrict__ p0, const float* __restrict__ p1,
    const float* __restrict__ p2, const float* __restrict__ p3,
    const float* __restrict__ lemb,
    float* __restrict__ out, unsigned short* __restrict__ outbf,
    unsigned short* __restrict__ qbf, float* __restrict__ pos)
{
    int gid = blockIdx.x * 256 + threadIdx.x;
    if (gid >= MROWS * D_MODEL) return;
    int d  = gid & (D_MODEL - 1);
    int bt = gid >> 8;
    int b  = (bt >= LEN) ? 1 : 0;
    int t  = bt - b * LEN;

    int lv, li, hw;
    const float* sp; const float* pp;
    if (t < 2304)      { lv = 0; li = t;        hw = 2304; sp = s0; pp = p0; }
    else if (t < 2880) { lv = 1; li = t - 2304; hw = 576;  sp = s1; pp = p1; }
    else if (t < 3024) { lv = 2; li = t - 2880; hw = 144;  sp = s2; pp = p2; }
    else               { lv = 3; li = t - 3024; hw = 36;   sp = s3; pp = p3; }

    size_t si = (size_t)(b * D_MODEL + d) * hw + li;
    float v = sp[si];
    float pv = pp[si] + lemb[lv * D_MODEL + d];
    out[gid]   = v;
    outbf[gid] = f2bf(v);
    qbf[gid]   = f2bf(v + pv);
    pos[gid]   = pv;
}

// ---------------------------------------------------------------------------
__global__ __launch_bounds__(256) void wconv_kernel(
    const float* __restrict__ Wv, const float* __restrict__ Woff,
    const float* __restrict__ Wa, const float* __restrict__ Wo,
    const float* __restrict__ W1, const float* __restrict__ W2,
    unsigned short* __restrict__ Wv_t, unsigned short* __restrict__ Woffa_t,
    unsigned short* __restrict__ Wo_t, unsigned short* __restrict__ W1_t,
    unsigned short* __restrict__ W2_t)
{
    __shared__ float tile[32][33];
    int bid = blockIdx.x;
    int layer = bid / 736, r = bid % 736;
    const float* src; unsigned short* dst;
    int N, tk, tn, dstRowOff = 0, dstLd;
    if (r < 64)       { src = Wv  + layer*65536;  dst = Wv_t   + layer*65536;  N = 256;  int t2 = r;       tk = t2 >> 3; tn = t2 & 7;  dstLd = 256;  }
    else if (r < 128) { src = Woff+ layer*65536;  dst = Woffa_t+ layer*98304;  N = 256;  int t2 = r - 64;  tk = t2 >> 3; tn = t2 & 7;  dstLd = 256;  }
    else if (r < 160) { src = Wa  + layer*32768;  dst = Woffa_t+ layer*98304;  N = 128;  int t2 = r - 128; tk = t2 >> 2; tn = t2 & 3;  dstLd = 256;  dstRowOff = 256; }
    else if (r < 224) { src = Wo  + layer*65536;  dst = Wo_t   + layer*65536;  N = 256;  int t2 = r - 160; tk = t2 >> 3; tn = t2 & 7;  dstLd = 256;  }
    else if (r < 480) { src = W1  + layer*262144; dst = W1_t   + layer*262144; N = 1024; int t2 = r - 224; tk = t2 >> 5; tn = t2 & 31; dstLd = 256;  }
    else              { src = W2  + layer*262144; dst = W2_t   + layer*262144; N = 256;  int t2 = r - 480; tk = t2 >> 3; tn = t2 & 7;  dstLd = 1024; }
    int k0 = tk * 32, n0 = tn * 32;
    int tx = threadIdx.x & 31, ty = threadIdx.x >> 5;
    #pragma unroll
    for (int i = 0; i < 4; ++i)
        tile[ty + i*8][tx] = src[(size_t)(k0 + ty + i*8) * N + n0 + tx];
    __syncthreads();
    #pragma unroll
    for (int i = 0; i < 4; ++i)
        dst[(size_t)(dstRowOff + n0 + ty + i*8) * dstLd + k0 + tx] =
            f2bf(tile[tx][ty + i*8]);
}

// ---------------------------------------------------------------------------
// GEMM building blocks: 64x64 tile, K-chunk 256 staged to LDS (A 32KB @0,
// B 32KB @32768), fragment-major, conflict-free b128 reads. 4 waves (2x2).
// ---------------------------------------------------------------------------
__device__ __forceinline__ void stage_tile(
    const unsigned short* __restrict__ P, int ld, int first, int kb, char* dst)
{
    const int tid = threadIdx.x;
    #pragma unroll
    for (int i = 0; i < 8; ++i) {
        int c = i * 256 + tid, q = c >> 6, r = c & 63;
        GLDS(P + (size_t)(first + r) * ld + kb + q * 8, dst + c * 16);
    }
}

__device__ __forceinline__ void compute_fk(const char* smem, f32x4 (&acc)[2][2])
{
    const int lane = threadIdx.x & 63, wave = threadIdx.x >> 6;
    const int wm = wave >> 1, wn = wave & 1;
    const int l15 = lane & 15, l4 = lane >> 4;
    #pragma unroll
    for (int kf = 0; kf < 8; ++kf) {
        const int q = kf * 4 + l4;
        bf16x8 av[2], bv[2];
        av[0] = *(const bf16x8*)(smem + (q*64 + wm*32      + l15) * 16);
        av[1] = *(const bf16x8*)(smem + (q*64 + wm*32 + 16 + l15) * 16);
        bv[0] = *(const bf16x8*)(smem + 32768 + (q*64 + wn*32      + l15) * 16);
        bv[1] = *(const bf16x8*)(smem + 32768 + (q*64 + wn*32 + 16 + l15) * 16);
        #pragma unroll
        for (int mf = 0; mf < 2; ++mf)
            #pragma unroll
            for (int nf = 0; nf < 2; ++nf)
                acc[mf][nf] = __builtin_amdgcn_mfma_f32_16x16x32_bf16(
                    av[mf], bv[nf], acc[mf][nf], 0, 0, 0);
    }
}

// ---------------------------------------------------------------------------
// Persistent GEMM (K=256): B staged once, loop over PANELS row-panels.
// grid (N/64, 96/PANELS). 2 blocks/CU -> stage/compute overlap across blocks.
// ---------------------------------------------------------------------------
template<int PANELS, bool RELU, bool OUTBF>
__global__ __launch_bounds__(256) void pgemm(
    const unsigned short* __restrict__ A, const unsigned short* __restrict__ Bt,
    const float* __restrict__ bias, void* __restrict__ Cout, int N)
{
    __shared__ __align__(16) char smem[65536];
    int tx, ty; swz_xy(tx, ty);
    const int col0 = tx * 64;
    const int lane = threadIdx.x & 63, wave = threadIdx.x >> 6;
    const int wm = wave >> 1, wn = wave & 1;
    const int l15 = lane & 15, l4 = lane >> 4;

    stage_tile(Bt, 256, col0, 0, smem + 32768);
    #pragma unroll 1
    for (int p = 0; p < PANELS; ++p) {
        const int row0 = (ty * PANELS + p) * 64;
        stage_tile(A, 256, row0, 0, smem);
        __syncthreads();
        f32x4 acc[2][2] = {};
        compute_fk(smem, acc);
        __syncthreads();
        #pragma unroll
        for (int nf = 0; nf < 2; ++nf) {
            int col = col0 + wn*32 + nf*16 + l15;
            float bb = bias[col];
            #pragma unroll
            for (int mf = 0; mf < 2; ++mf)
                #pragma unroll
                for (int i = 0; i < 4; ++i) {
                    int row = row0 + wm*32 + mf*16 + l4*4 + i;
                    if (row < MROWS) {
                        float v = acc[mf][nf][i] + bb;
                        if (RELU) v = fmaxf(v, 0.f);
                        if (OUTBF)
                            ((unsigned short*)Cout)[(size_t)row * N + col] = f2bf(v);
                        else
                            ((float*)Cout)[(size_t)row * N + col] = v;
                    }
                }
        }
    }
}

// ---------------------------------------------------------------------------
// Persistent VA GEMM: grid (10, 48), PANELS=2. tx<4: value -> bf16 valbf
// (N=256). tx>=4: offattn -> fp32 (N=384), attn cols softmaxed in-fragment.
// ---------------------------------------------------------------------------
__global__ __launch_bounds__(256) void pgemm_va(
    const unsigned short* __restrict__ outbf, const unsigned short* __restrict__ qbf,
    const unsigned short* __restrict__ Wv_l, const unsigned short* __restrict__ Woffa_l,
    const float* __restrict__ bv, const float* __restrict__ boff,
    const float* __restrict__ ba,
    unsigned short* __restrict__ valbf, float* __restrict__ offattn)
{
    __shared__ __align__(16) char smem[65536];
    int tx, ty; swz_xy(tx, ty);
    const bool isV = tx < 4;
    const unsigned short* A  = isV ? outbf : qbf;
    const unsigned short* Bt = isV ? Wv_l : Woffa_l;
    const int col0 = isV ? tx * 64 : (tx - 4) * 64;
    const int lane = threadIdx.x & 63, wave = threadIdx.x >> 6;
    const int wm = wave >> 1, wn = wave & 1;
    const int l15 = lane & 15, l4 = lane >> 4;

    stage_tile(Bt, 256, col0, 0, smem + 32768);
    #pragma unroll 1
    for (int p = 0; p < 2; ++p) {
        const int row0 = (ty * 2 + p) * 64;
        stage_tile(A, 256, row0, 0, smem);
        __syncthreads();
        f32x4 acc[2][2] = {};
        compute_fk(smem, acc);
        __syncthreads();
        #pragma unroll
        for (int nf = 0; nf < 2; ++nf) {
            int base = col0 + wn*32 + nf*16;
            int col  = base + l15;
            float bb = isV ? bv[col] : (col < 256 ? boff[col] : ba[col - 256]);
            const bool isAttn = (!isV) && (base >= 256);
            #pragma unroll
            for (int mf = 0; mf < 2; ++mf)
                #pragma unroll
                for (int i = 0; i < 4; ++i) {
                    int row = row0 + wm*32 + mf*16 + l4*4 + i;
                    float v = acc[mf][nf][i] + bb;
                    if (isAttn) {
                        float mx = v;
                        #pragma unroll
                        for (int m = 1; m < 16; m <<= 1)
                            mx = fmaxf(mx, __shfl_xor(mx, m));
                        float e = __expf(v - mx);
                        float s = e;
                        #pragma unroll
                        for (int m = 1; m < 16; m <<= 1)
                            s += __shfl_xor(s, m);
                        v = e / s;
                    }
                    if (row < MROWS) {
                        if (isV)
                            valbf[(size_t)row * 256 + col] = f2bf(v);
                        else
                            offattn[(size_t)row * 384 + col] = v;
                    }
                }
        }
    }
}

// ---------------------------------------------------------------------------
// FFN2 GEMM (K=1024, split-K=2): grid (8, 96); tx&3 = col-tile, tx>>2 = s.
// ---------------------------------------------------------------------------
__global__ __launch_bounds__(256) void gemm_ffn2(
    const unsigned short* __restrict__ hbuf, const unsigned short* __restrict__ W2_t,
    const float* __restrict__ bias, float* __restrict__ part)
{
    __shared__ __align__(16) char smem[65536];
    int tx, ty; swz_xy(tx, ty);
    const int ct = tx & 3, s = tx >> 2;
    const int row0 = ty * 64, col0 = ct * 64;
    const int lane = threadIdx.x & 63, wave = threadIdx.x >> 6;
    const int wm = wave >> 1, wn = wave & 1;
    const int l15 = lane & 15, l4 = lane >> 4;

    f32x4 acc[2][2] = {};
    #pragma unroll 1
    for (int c = 0; c < 2; ++c) {
        const int kb = s * 512 + c * 256;
        stage_tile(hbuf, 1024, row0, kb, smem);
        stage_tile(W2_t, 1024, col0, kb, smem + 32768);
        __syncthreads();
        compute_fk(smem, acc);
        __syncthreads();
    }

    float* dst = part + (size_t)s * PSTRIDE;
    #pragma unroll
    for (int nf = 0; nf < 2; ++nf) {
        int col = col0 + wn*32 + nf*16 + l15;
        float bb = (s == 0) ? bias[col] : 0.f;
        #pragma unroll
        for (int mf = 0; mf < 2; ++mf)
            #pragma unroll
            for (int i = 0; i < 4; ++i) {
                int row = row0 + wm*32 + mf*16 + l4*4 + i;
                if (row < MROWS)
                    dst[(size_t)row * 256 + col] = acc[mf][nf][i] + bb;
            }
    }
}

// ---------------------------------------------------------------------------
// MSDA sampling: thread = (token, head, 16-dim half); all gathers 16B.
// Attn weights pre-normalized by pgemm_va. [xREP_MSDA diagnostic]
// ---------------------------------------------------------------------------
template<int REPS>
__global__ __launch_bounds__(256) void msda_kernel(
    const unsigned short* __restrict__ value,  // (b*t, 256) bf16
    const float* __restrict__ offattn,         // (b*t, 384)
    unsigned short* __restrict__ outb)         // (b*t, 256) bf16
{
    int gid = blockIdx.x * 256 + threadIdx.x;
    if (gid >= MROWS * 16) return;
    int half = gid & 1;
    int h    = (gid >> 1) & 7;
    int bt   = gid >> 4;
    int b    = (bt >= LEN) ? 1 : 0;
    int t    = bt - b * LEN;

    int li, Wr;
    if (t < 2304)      { li = t;        Wr = 48; }
    else if (t < 2880) { li = t - 2304; Wr = 24; }
    else if (t < 3024) { li = t - 2880; Wr = 12; }
    else               { li = t - 3024; Wr = 6;  }
    float refx = ((li % Wr) + 0.5f) / (float)Wr;
    float refy = ((li / Wr) + 0.5f) / (float)Wr;

    const int starts[4] = {0, 2304, 2880, 3024};
    const int Ws[4]     = {48, 24, 12, 6};

    #pragma unroll 1
    for (int rep = 0; rep < REPS; ++rep) {
        const unsigned short* val_r = launder_p(value);
        const float* oa_r = launder_p(offattn);
        const float* lg   = oa_r + (size_t)bt * 384 + 256 + h * 16;
        const float* offp = oa_r + (size_t)bt * 384 + h * 32;
        const unsigned short* valbase =
            val_r + (size_t)b * LEN * D_MODEL + h * HDIM + half * 16;

        float acc[16];
        #pragma unroll
        for (int j = 0; j < 16; ++j) acc[j] = 0.f;

        #pragma unroll
        for (int lv = 0; lv < NLVL; ++lv) {
            int Wl = Ws[lv];
            int stt = starts[lv];
            float fW = (float)Wl;
            #pragma unroll
            for (int p = 0; p < NPTS; ++p) {
                float ox = offp[(lv * NPTS + p) * 2 + 0];
                float oy = offp[(lv * NPTS + p) * 2 + 1];
                float aw = lg[lv * NPTS + p];
                float x = (refx + ox / fW) * fW - 0.5f;
                float y = (refy + oy / fW) * fW - 0.5f;
                float x0f = floorf(x), y0f = floorf(y);
                float lx = x - x0f, ly = y - y0f;
                int x0 = (int)x0f, y0 = (int)y0f;
                float tw[4] = {(1.f - lx) * (1.f - ly), lx * (1.f - ly),
                               (1.f - lx) * ly,         lx * ly};
                const int dxs[4] = {0, 1, 0, 1};
                const int dys[4] = {0, 0, 1, 1};
                #pragma unroll
                for (int tap = 0; tap < 4; ++tap) {
                    int xi = x0 + dxs[tap], yi = y0 + dys[tap];
                    bool valid = (xi >= 0) & (xi < Wl) & (yi >= 0) & (yi < Wl);
                    int xc = xi < 0 ? 0 : (xi > Wl - 1 ? Wl - 1 : xi);
                    int yc = yi < 0 ? 0 : (yi > Wl - 1 ? Wl - 1 : yi);
                    int tt = stt + yc * Wl + xc;
                    const bf16x8* vp =
                        (const bf16x8*)(valbase + (size_t)tt * D_MODEL);
                    bf16x8 va = vp[0], vb = vp[1];
                    float wt = valid ? aw * tw[tap] : 0.f;
                    #pragma unroll
                    for (int j = 0; j < 8; ++j) {
                        acc[j]     += wt * bf2f((unsigned short)va[j]);
                        acc[8 + j] += wt * bf2f((unsigned short)vb[j]);
                    }
                }
            }
        }
        bf16x8 o0, o1;
        #pragma unroll
        for (int j = 0; j < 8; ++j) {
            o0[j] = (short)f2bf(acc[j]);
            o1[j] = (short)f2bf(acc[8 + j]);
        }
        bf16x8* op = (bf16x8*)(outb + (size_t)bt * D_MODEL + h * HDIM + half * 16);
        op[0] = o0; op[1] = o1;
    }
}

// ---------------------------------------------------------------------------
template<int NPART, bool WITH_POS>
__global__ __launch_bounds__(256) void add_ln_kernel(
    float* __restrict__ out, unsigned short* __restrict__ outbf,
    const float* __restrict__ part,
    const float* __restrict__ g, const float* __restrict__ be,
    const float* __restrict__ pos, unsigned short* __restrict__ qbf)
{
    int row  = blockIdx.x * 4 + (threadIdx.x >> 6);
    int lane = threadIdx.x & 63;
    if (row >= MROWS) return;

    float4 x = ((const float4*)(out + (size_t)row * D_MODEL))[lane];
    float4 y = ((const float4*)(part + (size_t)row * D_MODEL))[lane];
    x.x += y.x; x.y += y.y; x.z += y.z; x.w += y.w;
    if (NPART == 2) {
        float4 z = ((const float4*)(part + PSTRIDE + (size_t)row * D_MODEL))[lane];
        x.x += z.x; x.y += z.y; x.z += z.z; x.w += z.w;
    }

    float s  = x.x + x.y + x.z + x.w;
    float ss = x.x * x.x + x.y * x.y + x.z * x.z + x.w * x.w;
    #pragma unroll
    for (int m = 1; m < 64; m <<= 1) {
        s  += __shfl_xor(s, m);
        ss += __shfl_xor(ss, m);
    }
    float mean = s * (1.f / 256.f);
    float var  = ss * (1.f / 256.f) - mean * mean;
    float rstd = rsqrtf(var + 1e-5f);

    float4 gv = ((const float4*)g)[lane];
    float4 bv = ((const float4*)be)[lane];
    float4 o;
    o.x = (x.x - mean) * rstd * gv.x + bv.x;
    o.y = (x.y - mean) * rstd * gv.y + bv.y;
    o.z = (x.z - mean) * rstd * gv.z + bv.z;
    o.w = (x.w - mean) * rstd * gv.w + bv.w;
    ((float4*)(out + (size_t)row * D_MODEL))[lane] = o;
    ((ushort4*)(outbf + (size_t)row * D_MODEL))[lane] =
        make_ushort4(f2bf(o.x), f2bf(o.y), f2bf(o.z), f2bf(o.w));
    if (WITH_POS) {
        float4 pv = ((const float4*)(pos + (size_t)row * D_MODEL))[lane];
        ((ushort4*)(qbf + (size_t)row * D_MODEL))[lane] =
            make_ushort4(f2bf(o.x + pv.x), f2bf(o.y + pv.y),
                         f2bf(o.z + pv.z), f2bf(o.w + pv.w));
    }
}

// ---------------------------------------------------------------------------
__global__ void tail_kernel(float* __restrict__ tail)
{
    if (threadIdx.x == 0 && blockIdx.x == 0) {
        const float vals[12] = {48.f, 48.f, 24.f, 24.f, 12.f, 12.f, 6.f, 6.f,
                                0.f, 2304.f, 2880.f, 3024.f};
        #pragma unroll
        for (int i = 0; i < 12; ++i) tail[i] = vals[i];
    }
}

// ---------------------------------------------------------------------------
extern "C" void kernel_launch(void* const* d_in, const int* in_sizes, int n_in,
                              void* d_out, int out_size, void* d_ws, size_t ws_size,
                              hipStream_t stream)
{
    const float* SRC[4]; const float* POS[4];
    bool interleaved = (in_sizes[1] == in_sizes[0]);
    if (interleaved) {
        SRC[0] = (const float*)d_in[0]; POS[0] = (const float*)d_in[1];
        SRC[1] = (const float*)d_in[2]; POS[1] = (const float*)d_in[3];
        SRC[2] = (const float*)d_in[4]; POS[2] = (const float*)d_in[5];
        SRC[3] = (const float*)d_in[6]; POS[3] = (const float*)d_in[7];
    } else {
        for (int i = 0; i < 4; ++i) {
            SRC[i] = (const float*)d_in[i];
            POS[i] = (const float*)d_in[4 + i];
        }
    }
    const float* lemb  = (const float*)d_in[8];
    const float* Wv    = (const float*)d_in[9];
    const float* bv    = (const float*)d_in[10];
    const float* Woff  = (const float*)d_in[11];
    const float* boff  = (const float*)d_in[12];
    const float* Wa    = (const float*)d_in[13];
    const float* ba    = (const float*)d_in[14];
    const float* Wo    = (const float*)d_in[15];
    const float* bo    = (const float*)d_in[16];
    const float* g1    = (const float*)d_in[17];
    const float* beta1 = (const float*)d_in[18];
    const float* W1    = (const float*)d_in[19];
    const float* bf1   = (const float*)d_in[20];
    const float* W2    = (const float*)d_in[21];
    const float* bf2   = (const float*)d_in[22];
    const float* g2    = (const float*)d_in[23];
    const float* beta2 = (const float*)d_in[24];

    float* out = (float*)d_out;

    char* ws = (char*)d_ws;
    float* pos     = (float*)ws;                   ws += (size_t)MPAD * 256 * 4;
    float* offattn = (float*)ws;                   ws += (size_t)MPAD * 384 * 4;
    float* part    = (float*)ws;                   ws += 2 * PSTRIDE * 4;
    unsigned short* qbf    = (unsigned short*)ws;  ws += (size_t)MPAD * 256 * 2;
    unsigned short* outbf  = (unsigned short*)ws;  ws += (size_t)MPAD * 256 * 2;
    unsigned short* msdabf = (unsigned short*)ws;  ws += (size_t)MPAD * 256 * 2;
    unsigned short* valbf  = (unsigned short*)ws;  ws += (size_t)MPAD * 256 * 2;
    unsigned short* hbuf   = (unsigned short*)ws;  ws += (size_t)MPAD * 1024 * 2;
    unsigned short* Wv_t    = (unsigned short*)ws; ws += (size_t)6 * 65536 * 2;
    unsigned short* Woffa_t = (unsigned short*)ws; ws += (size_t)6 * 98304 * 2;
    unsigned short* Wo_t    = (unsigned short*)ws; ws += (size_t)6 * 65536 * 2;
    unsigned short* W1_t    = (unsigned short*)ws; ws += (size_t)6 * 262144 * 2;
    unsigned short* W2_t    = (unsigned short*)ws; ws += (size_t)6 * 262144 * 2;

    wconv_kernel<<<6 * 736, 256, 0, stream>>>(Wv, Woff, Wa, Wo, W1, W2,
                                              Wv_t, Woffa_t, Wo_t, W1_t, W2_t);

    const int nElem = MROWS * D_MODEL;
    flatten_kernel<<<(nElem + 255) / 256, 256, 0, stream>>>(
        SRC[0], SRC[1], SRC[2], SRC[3], POS[0], POS[1], POS[2], POS[3],
        lemb, out, outbf, qbf, pos);

    const dim3 gVA(10, 48);             // PANELS=2 -> 480 blocks
    const dim3 gWo(4, 48);              // PANELS=2 -> 192 blocks
    const dim3 gF1(16, 32);             // PANELS=3 -> 512 blocks
    const dim3 gF2(8, 96);              // 768 blocks
    const int gMS = (MROWS * 16 + 255) / 256;   // 383
    const int gLN = MROWS / 4;          // 1530

    for (int l = 0; l < NLAYERS; ++l) {
        const unsigned short* Wv_l    = Wv_t    + (size_t)l * 65536;
        const unsigned short* Woffa_l = Woffa_t + (size_t)l * 98304;
        const unsigned short* Wo_l    = Wo_t    + (size_t)l * 65536;
        const unsigned short* W1_l    = W1_t    + (size_t)l * 262144;
        const unsigned short* W2_l    = W2_t    + (size_t)l * 262144;

        pgemm_va<<<gVA, 256, 0, stream>>>(
            outbf, qbf, Wv_l, Woffa_l, bv + l * 256, boff + l * 256,
            ba + l * 128, valbf, offattn);

        msda_kernel<REP_MSDA><<<gMS, 256, 0, stream>>>(valbf, offattn, msdabf);

        pgemm<2, false, false><<<gWo, 256, 0, stream>>>(
            msdabf, Wo_l, bo + l * 256, part, 256);

        add_ln_kernel<1, false><<<gLN, 256, 0, stream>>>(
            out, outbf, part, g1 + l * 256, beta1 + l * 256, pos, qbf);

        pgemm<3, true, true><<<gF1, 256, 0, stream>>>(
            outbf, W1_l, bf1 + l * DFF, hbuf, 1024);

        gemm_ffn2<<<gF2, 256, 0, stream>>>(hbuf, W2_l, bf2 + l * 256, part);

        add_ln_kernel<2, true><<<gLN, 256, 0, stream>>>(
            out, outbf, part, g2 + l * 256, beta2 + l * 256, pos, qbf);
    }

    tail_kernel<<<1, 64, 0, stream>>>(out + (size_t)MROWS * D_MODEL);
}

// Round 8
// 660.851 us; speedup vs baseline: 1.6618x; 1.6618x over previous
//
#include <hip/hip_runtime.h>
#include <math.h>

#define D_MODEL 256
#define NHEAD 8
#define HDIM 32
#define NLVL 4
#define NPTS 4
#define DFF 1024
#define NLAYERS 6
#define LEN 3060
#define BS 2
#define MROWS (BS * LEN)   // 6120
#define MPAD 6144
#define PSTRIDE ((size_t)MPAD * 256)

typedef __attribute__((ext_vector_type(8))) short bf16x8;
typedef __attribute__((ext_vector_type(4))) float f32x4;

__device__ __forceinline__ unsigned short f2bf(float f) {
    union { float f; unsigned u; } v; v.f = f;
    unsigned r = v.u + 0x7FFF + ((v.u >> 16) & 1);
    return (unsigned short)(r >> 16);
}
__device__ __forceinline__ float bf2f(unsigned short s) {
    union { unsigned u; float f; } v; v.u = ((unsigned)s) << 16;
    return v.f;
}

#define GLDS(gp, lp) __builtin_amdgcn_global_load_lds(                        \
    (const __attribute__((address_space(1))) void*)(gp),                      \
    (__attribute__((address_space(3))) void*)(lp), 16, 0, 0)

// XCD-bijective block swizzle (nwg % 8 == 0)
__device__ __forceinline__ void swz_xy(int& tx, int& ty) {
    const int gx = gridDim.x;
    const int id = blockIdx.y * gx + blockIdx.x;
    const int q  = (gx * gridDim.y) >> 3;
    const int L  = (id & 7) * q + (id >> 3);
    ty = L / gx; tx = L - ty * gx;
}

// ---------------------------------------------------------------------------
// Flatten: src levels -> outbf, qbf = bf16(src+pos), posbf
// ---------------------------------------------------------------------------
__global__ __launch_bounds__(256) void flatten_kernel(
    const float* __restrict__ s0, const float* __restrict__ s1,
    const float* __restrict__ s2, const float* __restrict__ s3,
    const float* __restrict__ p0, const float* __restrict__ p1,
    const float* __restrict__ p2, const float* __restrict__ p3,
    const float* __restrict__ lemb,
    unsigned short* __restrict__ outbf, unsigned short* __restrict__ qbf,
    unsigned short* __restrict__ posbf)
{
    int gid = blockIdx.x * 256 + threadIdx.x;
    if (gid >= MROWS * D_MODEL) return;
    int d  = gid & (D_MODEL - 1);
    int bt = gid >> 8;
    int b  = (bt >= LEN) ? 1 : 0;
    int t  = bt - b * LEN;

    int lv, li, hw;
    const float* sp; const float* pp;
    if (t < 2304)      { lv = 0; li = t;        hw = 2304; sp = s0; pp = p0; }
    else if (t < 2880) { lv = 1; li = t - 2304; hw = 576;  sp = s1; pp = p1; }
    else if (t < 3024) { lv = 2; li = t - 2880; hw = 144;  sp = s2; pp = p2; }
    else               { lv = 3; li = t - 3024; hw = 36;   sp = s3; pp = p3; }

    size_t si = (size_t)(b * D_MODEL + d) * hw + li;
    float v = sp[si];
    float pv = pp[si] + lemb[lv * D_MODEL + d];
    outbf[gid] = f2bf(v);
    qbf[gid]   = f2bf(v + pv);
    posbf[gid] = f2bf(pv);
}

// ---------------------------------------------------------------------------
__global__ __launch_bounds__(256) void wconv_kernel(
    const float* __restrict__ Wv, const float* __restrict__ Woff,
    const float* __restrict__ Wa, const float* __restrict__ Wo,
    const float* __restrict__ W1, const float* __restrict__ W2,
    unsigned short* __restrict__ Wv_t, unsigned short* __restrict__ Woffa_t,
    unsigned short* __restrict__ Wo_t, unsigned short* __restrict__ W1_t,
    unsigned short* __restrict__ W2_t)
{
    __shared__ float tile[32][33];
    int bid = blockIdx.x;
    int layer = bid / 736, r = bid % 736;
    const float* src; unsigned short* dst;
    int N, tk, tn, dstRowOff = 0, dstLd;
    if (r < 64)       { src = Wv  + layer*65536;  dst = Wv_t   + layer*65536;  N = 256;  int t2 = r;       tk = t2 >> 3; tn = t2 & 7;  dstLd = 256;  }
    else if (r < 128) { src = Woff+ layer*65536;  dst = Woffa_t+ layer*98304;  N = 256;  int t2 = r - 64;  tk = t2 >> 3; tn = t2 & 7;  dstLd = 256;  }
    else if (r < 160) { src = Wa  + layer*32768;  dst = Woffa_t+ layer*98304;  N = 128;  int t2 = r - 128; tk = t2 >> 2; tn = t2 & 3;  dstLd = 256;  dstRowOff = 256; }
    else if (r < 224) { src = Wo  + layer*65536;  dst = Wo_t   + layer*65536;  N = 256;  int t2 = r - 160; tk = t2 >> 3; tn = t2 & 7;  dstLd = 256;  }
    else if (r < 480) { src = W1  + layer*262144; dst = W1_t   + layer*262144; N = 1024; int t2 = r - 224; tk = t2 >> 5; tn = t2 & 31; dstLd = 256;  }
    else              { src = W2  + layer*262144; dst = W2_t   + layer*262144; N = 256;  int t2 = r - 480; tk = t2 >> 3; tn = t2 & 7;  dstLd = 1024; }
    int k0 = tk * 32, n0 = tn * 32;
    int tx = threadIdx.x & 31, ty = threadIdx.x >> 5;
    #pragma unroll
    for (int i = 0; i < 4; ++i)
        tile[ty + i*8][tx] = src[(size_t)(k0 + ty + i*8) * N + n0 + tx];
    __syncthreads();
    #pragma unroll
    for (int i = 0; i < 4; ++i)
        dst[(size_t)(dstRowOff + n0 + ty + i*8) * dstLd + k0 + tx] =
            f2bf(tile[tx][ty + i*8]);
}

// ---------------------------------------------------------------------------
// GEMM building blocks (64x64 tile, K-chunk 256, conflict-free b128 frags)
// ---------------------------------------------------------------------------
__device__ __forceinline__ void stage_tile(
    const unsigned short* __restrict__ P, int ld, int first, int kb, char* dst)
{
    const int tid = threadIdx.x;
    #pragma unroll
    for (int i = 0; i < 8; ++i) {
        int c = i * 256 + tid, q = c >> 6, r = c & 63;
        GLDS(P + (size_t)(first + r) * ld + kb + q * 8, dst + c * 16);
    }
}

__device__ __forceinline__ void compute_fk(const char* smem, f32x4 (&acc)[2][2])
{
    const int lane = threadIdx.x & 63, wave = threadIdx.x >> 6;
    const int wm = wave >> 1, wn = wave & 1;
    const int l15 = lane & 15, l4 = lane >> 4;
    #pragma unroll
    for (int kf = 0; kf < 8; ++kf) {
        const int q = kf * 4 + l4;
        bf16x8 av[2], bv[2];
        av[0] = *(const bf16x8*)(smem + (q*64 + wm*32      + l15) * 16);
        av[1] = *(const bf16x8*)(smem + (q*64 + wm*32 + 16 + l15) * 16);
        bv[0] = *(const bf16x8*)(smem + 32768 + (q*64 + wn*32      + l15) * 16);
        bv[1] = *(const bf16x8*)(smem + 32768 + (q*64 + wn*32 + 16 + l15) * 16);
        #pragma unroll
        for (int mf = 0; mf < 2; ++mf)
            #pragma unroll
            for (int nf = 0; nf < 2; ++nf)
                acc[mf][nf] = __builtin_amdgcn_mfma_f32_16x16x32_bf16(
                    av[mf], bv[nf], acc[mf][nf], 0, 0, 0);
    }
}

// ---------------------------------------------------------------------------
// Persistent GEMM (K=256): B staged once, loop PANELS row-panels.
// ---------------------------------------------------------------------------
template<int PANELS, bool RELU, bool OUTBF>
__global__ __launch_bounds__(256) void pgemm(
    const unsigned short* __restrict__ A, const unsigned short* __restrict__ Bt,
    const float* __restrict__ bias, void* __restrict__ Cout, int N)
{
    __shared__ __align__(16) char smem[65536];
    int tx, ty; swz_xy(tx, ty);
    const int col0 = tx * 64;
    const int lane = threadIdx.x & 63, wave = threadIdx.x >> 6;
    const int wm = wave >> 1, wn = wave & 1;
    const int l15 = lane & 15, l4 = lane >> 4;

    stage_tile(Bt, 256, col0, 0, smem + 32768);
    #pragma unroll 1
    for (int p = 0; p < PANELS; ++p) {
        const int row0 = (ty * PANELS + p) * 64;
        stage_tile(A, 256, row0, 0, smem);
        __syncthreads();
        f32x4 acc[2][2] = {};
        compute_fk(smem, acc);
        __syncthreads();
        #pragma unroll
        for (int nf = 0; nf < 2; ++nf) {
            int col = col0 + wn*32 + nf*16 + l15;
            float bb = bias[col];
            #pragma unroll
            for (int mf = 0; mf < 2; ++mf)
                #pragma unroll
                for (int i = 0; i < 4; ++i) {
                    int row = row0 + wm*32 + mf*16 + l4*4 + i;
                    if (row < MROWS) {
                        float v = acc[mf][nf][i] + bb;
                        if (RELU) v = fmaxf(v, 0.f);
                        if (OUTBF)
                            ((unsigned short*)Cout)[(size_t)row * N + col] = f2bf(v);
                        else
                            ((float*)Cout)[(size_t)row * N + col] = v;
                    }
                }
        }
    }
}

// ---------------------------------------------------------------------------
// Persistent VA GEMM: grid (10, 48), PANELS=2. tx<4: value -> HEAD-MAJOR bf16
// valbf[b][h][t][32]. tx>=4: offattn fp32 (N=384), attn cols softmaxed.
// ---------------------------------------------------------------------------
__global__ __launch_bounds__(256) void pgemm_va(
    const unsigned short* __restrict__ outbf, const unsigned short* __restrict__ qbf,
    const unsigned short* __restrict__ Wv_l, const unsigned short* __restrict__ Woffa_l,
    const float* __restrict__ bv, const float* __restrict__ boff,
    const float* __restrict__ ba,
    unsigned short* __restrict__ valbf, float* __restrict__ offattn)
{
    __shared__ __align__(16) char smem[65536];
    int tx, ty; swz_xy(tx, ty);
    const bool isV = tx < 4;
    const unsigned short* A  = isV ? outbf : qbf;
    const unsigned short* Bt = isV ? Wv_l : Woffa_l;
    const int col0 = isV ? tx * 64 : (tx - 4) * 64;
    const int lane = threadIdx.x & 63, wave = threadIdx.x >> 6;
    const int wm = wave >> 1, wn = wave & 1;
    const int l15 = lane & 15, l4 = lane >> 4;

    stage_tile(Bt, 256, col0, 0, smem + 32768);
    #pragma unroll 1
    for (int p = 0; p < 2; ++p) {
        const int row0 = (ty * 2 + p) * 64;
        stage_tile(A, 256, row0, 0, smem);
        __syncthreads();
        f32x4 acc[2][2] = {};
        compute_fk(smem, acc);
        __syncthreads();
        #pragma unroll
        for (int nf = 0; nf < 2; ++nf) {
            int base = col0 + wn*32 + nf*16;
            int col  = base + l15;
            float bb = isV ? bv[col] : (col < 256 ? boff[col] : ba[col - 256]);
            const bool isAttn = (!isV) && (base >= 256);
            #pragma unroll
            for (int mf = 0; mf < 2; ++mf)
                #pragma unroll
                for (int i = 0; i < 4; ++i) {
                    int row = row0 + wm*32 + mf*16 + l4*4 + i;
                    float v = acc[mf][nf][i] + bb;
                    if (isAttn) {
                        float mx = v;
                        #pragma unroll
                        for (int m = 1; m < 16; m <<= 1)
                            mx = fmaxf(mx, __shfl_xor(mx, m));
                        float e = __expf(v - mx);
                        float s = e;
                        #pragma unroll
                        for (int m = 1; m < 16; m <<= 1)
                            s += __shfl_xor(s, m);
                        v = e / s;
                    }
                    if (row < MROWS) {
                        if (isV) {
                            int b_ = row >= LEN ? 1 : 0;
                            int t_ = row - b_ * LEN;
                            valbf[((size_t)(b_*8 + (col >> 5)) * LEN + t_) * 32
                                  + (col & 31)] = f2bf(v);
                        } else {
                            offattn[(size_t)row * 384 + col] = v;
                        }
                    }
                }
        }
    }
}

// ---------------------------------------------------------------------------
// FFN2 GEMM (K=1024, split-K=2) -> bf16 partials
// ---------------------------------------------------------------------------
__global__ __launch_bounds__(256) void gemm_ffn2(
    const unsigned short* __restrict__ hbuf, const unsigned short* __restrict__ W2_t,
    const float* __restrict__ bias, unsigned short* __restrict__ part)
{
    __shared__ __align__(16) char smem[65536];
    int tx, ty; swz_xy(tx, ty);
    const int ct = tx & 3, s = tx >> 2;
    const int row0 = ty * 64, col0 = ct * 64;
    const int lane = threadIdx.x & 63, wave = threadIdx.x >> 6;
    const int wm = wave >> 1, wn = wave & 1;
    const int l15 = lane & 15, l4 = lane >> 4;

    f32x4 acc[2][2] = {};
    #pragma unroll 1
    for (int c = 0; c < 2; ++c) {
        const int kb = s * 512 + c * 256;
        stage_tile(hbuf, 1024, row0, kb, smem);
        stage_tile(W2_t, 1024, col0, kb, smem + 32768);
        __syncthreads();
        compute_fk(smem, acc);
        __syncthreads();
    }

    unsigned short* dst = part + (size_t)s * PSTRIDE;
    #pragma unroll
    for (int nf = 0; nf < 2; ++nf) {
        int col = col0 + wn*32 + nf*16 + l15;
        float bb = (s == 0) ? bias[col] : 0.f;
        #pragma unroll
        for (int mf = 0; mf < 2; ++mf)
            #pragma unroll
            for (int i = 0; i < 4; ++i) {
                int row = row0 + wm*32 + mf*16 + l4*4 + i;
                if (row < MROWS)
                    dst[(size_t)row * 256 + col] = f2bf(acc[mf][nf][i] + bb);
            }
    }
}

// ---------------------------------------------------------------------------
// MSDA sampling, head-major value. Thread = (token, head, 16-dim half).
// Per tap: two 16B loads from one 64B region; x-adjacent taps share lines.
// ---------------------------------------------------------------------------
__global__ __launch_bounds__(256) void msda_kernel(
    const unsigned short* __restrict__ value,  // (b,h,t,32) bf16
    const float* __restrict__ offattn,         // (b*t, 384)
    unsigned short* __restrict__ outb)         // (b*t, 256) bf16
{
    int gid = blockIdx.x * 256 + threadIdx.x;
    if (gid >= MROWS * 16) return;
    int half = gid & 1;
    int h    = (gid >> 1) & 7;
    int bt   = gid >> 4;
    int b    = (bt >= LEN) ? 1 : 0;
    int t    = bt - b * LEN;

    int li, Wr;
    if (t < 2304)      { li = t;        Wr = 48; }
    else if (t < 2880) { li = t - 2304; Wr = 24; }
    else if (t < 3024) { li = t - 2880; Wr = 12; }
    else               { li = t - 3024; Wr = 6;  }
    float refx = ((li % Wr) + 0.5f) / (float)Wr;
    float refy = ((li / Wr) + 0.5f) / (float)Wr;

    const int starts[4] = {0, 2304, 2880, 3024};
    const int Ws[4]     = {48, 24, 12, 6};

    const float* lg   = offattn + (size_t)bt * 384 + 256 + h * 16;
    const float* offp = offattn + (size_t)bt * 384 + h * 32;
    const unsigned short* valbase =
        value + ((size_t)(b * 8 + h) * LEN) * 32 + half * 16;

    float acc[16];
    #pragma unroll
    for (int j = 0; j < 16; ++j) acc[j] = 0.f;

    #pragma unroll
    for (int lv = 0; lv < NLVL; ++lv) {
        int Wl = Ws[lv];
        int stt = starts[lv];
        float fW = (float)Wl;
        #pragma unroll
        for (int p = 0; p < NPTS; ++p) {
            float ox = offp[(lv * NPTS + p) * 2 + 0];
            float oy = offp[(lv * NPTS + p) * 2 + 1];
            float aw = lg[lv * NPTS + p];
            float x = (refx + ox / fW) * fW - 0.5f;
            float y = (refy + oy / fW) * fW - 0.5f;
            float x0f = floorf(x), y0f = floorf(y);
            float lx = x - x0f, ly = y - y0f;
            int x0 = (int)x0f, y0 = (int)y0f;
            float tw[4] = {(1.f - lx) * (1.f - ly), lx * (1.f - ly),
                           (1.f - lx) * ly,         lx * ly};
            const int dxs[4] = {0, 1, 0, 1};
            const int dys[4] = {0, 0, 1, 1};
            #pragma unroll
            for (int tap = 0; tap < 4; ++tap) {
                int xi = x0 + dxs[tap], yi = y0 + dys[tap];
                bool valid = (xi >= 0) & (xi < Wl) & (yi >= 0) & (yi < Wl);
                int xc = xi < 0 ? 0 : (xi > Wl - 1 ? Wl - 1 : xi);
                int yc = yi < 0 ? 0 : (yi > Wl - 1 ? Wl - 1 : yi);
                int tt = stt + yc * Wl + xc;
                const bf16x8* vp = (const bf16x8*)(valbase + (size_t)tt * 32);
                bf16x8 va = vp[0], vb = vp[1];
                float wt = valid ? aw * tw[tap] : 0.f;
                #pragma unroll
                for (int j = 0; j < 8; ++j) {
                    acc[j]     += wt * bf2f((unsigned short)va[j]);
                    acc[8 + j] += wt * bf2f((unsigned short)vb[j]);
                }
            }
        }
    }
    bf16x8 o0, o1;
    #pragma unroll
    for (int j = 0; j < 8; ++j) {
        o0[j] = (short)f2bf(acc[j]);
        o1[j] = (short)f2bf(acc[8 + j]);
    }
    bf16x8* op = (bf16x8*)(outb + (size_t)bt * D_MODEL + h * HDIM + half * 16);
    op[0] = o0; op[1] = o1;
}

// ---------------------------------------------------------------------------
// Fused residual add (+partials, bf16) + LayerNorm on bf16 residual stream.
// WITH_POS: qbf = bf16(LN + pos). FINAL: write fp32 d_out + tail instead.
// ---------------------------------------------------------------------------
template<int NPART, bool WITH_POS, bool FINAL>
__global__ __launch_bounds__(256) void add_ln_kernel(
    unsigned short* __restrict__ outbf, const unsigned short* __restrict__ part,
    const float* __restrict__ g, const float* __restrict__ be,
    const unsigned short* __restrict__ posbf, unsigned short* __restrict__ qbf,
    float* __restrict__ outf)
{
    int row  = blockIdx.x * 4 + (threadIdx.x >> 6);
    int lane = threadIdx.x & 63;
    if (row >= MROWS) return;

    ushort4 xb = ((const ushort4*)(outbf + (size_t)row * D_MODEL))[lane];
    ushort4 pb = ((const ushort4*)(part + (size_t)row * D_MODEL))[lane];
    float4 x;
    x.x = bf2f(xb.x) + bf2f(pb.x);
    x.y = bf2f(xb.y) + bf2f(pb.y);
    x.z = bf2f(xb.z) + bf2f(pb.z);
    x.w = bf2f(xb.w) + bf2f(pb.w);
    if (NPART == 2) {
        ushort4 p2 = ((const ushort4*)(part + PSTRIDE + (size_t)row * D_MODEL))[lane];
        x.x += bf2f(p2.x); x.y += bf2f(p2.y);
        x.z += bf2f(p2.z); x.w += bf2f(p2.w);
    }

    float s  = x.x + x.y + x.z + x.w;
    float ss = x.x * x.x + x.y * x.y + x.z * x.z + x.w * x.w;
    #pragma unroll
    for (int m = 1; m < 64; m <<= 1) {
        s  += __shfl_xor(s, m);
        ss += __shfl_xor(ss, m);
    }
    float mean = s * (1.f / 256.f);
    float var  = ss * (1.f / 256.f) - mean * mean;
    float rstd = rsqrtf(var + 1e-5f);

    float4 gv = ((const float4*)g)[lane];
    float4 bv = ((const float4*)be)[lane];
    float4 o;
    o.x = (x.x - mean) * rstd * gv.x + bv.x;
    o.y = (x.y - mean) * rstd * gv.y + bv.y;
    o.z = (x.z - mean) * rstd * gv.z + bv.z;
    o.w = (x.w - mean) * rstd * gv.w + bv.w;

    if (FINAL) {
        ((float4*)(outf + (size_t)row * D_MODEL))[lane] = o;
        if (blockIdx.x == 0 && threadIdx.x < 12) {
            const float vals[12] = {48.f, 48.f, 24.f, 24.f, 12.f, 12.f,
                                    6.f, 6.f, 0.f, 2304.f, 2880.f, 3024.f};
            outf[(size_t)MROWS * D_MODEL + threadIdx.x] = vals[threadIdx.x];
        }
    } else {
        ((ushort4*)(outbf + (size_t)row * D_MODEL))[lane] =
            make_ushort4(f2bf(o.x), f2bf(o.y), f2bf(o.z), f2bf(o.w));
    }
    if (WITH_POS) {
        ushort4 pv = ((const ushort4*)(posbf + (size_t)row * D_MODEL))[lane];
        ((ushort4*)(qbf + (size_t)row * D_MODEL))[lane] =
            make_ushort4(f2bf(o.x + bf2f(pv.x)), f2bf(o.y + bf2f(pv.y)),
                         f2bf(o.z + bf2f(pv.z)), f2bf(o.w + bf2f(pv.w)));
    }
}

// ---------------------------------------------------------------------------
extern "C" void kernel_launch(void* const* d_in, const int* in_sizes, int n_in,
                              void* d_out, int out_size, void* d_ws, size_t ws_size,
                              hipStream_t stream)
{
    const float* SRC[4]; const float* POS[4];
    bool interleaved = (in_sizes[1] == in_sizes[0]);
    if (interleaved) {
        SRC[0] = (const float*)d_in[0]; POS[0] = (const float*)d_in[1];
        SRC[1] = (const float*)d_in[2]; POS[1] = (const float*)d_in[3];
        SRC[2] = (const float*)d_in[4]; POS[2] = (const float*)d_in[5];
        SRC[3] = (const float*)d_in[6]; POS[3] = (const float*)d_in[7];
    } else {
        for (int i = 0; i < 4; ++i) {
            SRC[i] = (const float*)d_in[i];
            POS[i] = (const float*)d_in[4 + i];
        }
    }
    const float* lemb  = (const float*)d_in[8];
    const float* Wv    = (const float*)d_in[9];
    const float* bv    = (const float*)d_in[10];
    const float* Woff  = (const float*)d_in[11];
    const float* boff  = (const float*)d_in[12];
    const float* Wa    = (const float*)d_in[13];
    const float* ba    = (const float*)d_in[14];
    const float* Wo    = (const float*)d_in[15];
    const float* bo    = (const float*)d_in[16];
    const float* g1    = (const float*)d_in[17];
    const float* beta1 = (const float*)d_in[18];
    const float* W1    = (const float*)d_in[19];
    const float* bf1   = (const float*)d_in[20];
    const float* W2    = (const float*)d_in[21];
    const float* bf2   = (const float*)d_in[22];
    const float* g2    = (const float*)d_in[23];
    const float* beta2 = (const float*)d_in[24];

    float* outf = (float*)d_out;   // fp32 final output (written by last LN)

    char* ws = (char*)d_ws;
    float* offattn = (float*)ws;                   ws += (size_t)MPAD * 384 * 4;
    unsigned short* part   = (unsigned short*)ws;  ws += 2 * PSTRIDE * 2;
    unsigned short* posbf  = (unsigned short*)ws;  ws += (size_t)MPAD * 256 * 2;
    unsigned short* qbf    = (unsigned short*)ws;  ws += (size_t)MPAD * 256 * 2;
    unsigned short* outbf  = (unsigned short*)ws;  ws += (size_t)MPAD * 256 * 2;
    unsigned short* msdabf = (unsigned short*)ws;  ws += (size_t)MPAD * 256 * 2;
    unsigned short* valbf  = (unsigned short*)ws;  ws += (size_t)MPAD * 256 * 2;
    unsigned short* hbuf   = (unsigned short*)ws;  ws += (size_t)MPAD * 1024 * 2;
    unsigned short* Wv_t    = (unsigned short*)ws; ws += (size_t)6 * 65536 * 2;
    unsigned short* Woffa_t = (unsigned short*)ws; ws += (size_t)6 * 98304 * 2;
    unsigned short* Wo_t    = (unsigned short*)ws; ws += (size_t)6 * 65536 * 2;
    unsigned short* W1_t    = (unsigned short*)ws; ws += (size_t)6 * 262144 * 2;
    unsigned short* W2_t    = (unsigned short*)ws; ws += (size_t)6 * 262144 * 2;

    wconv_kernel<<<6 * 736, 256, 0, stream>>>(Wv, Woff, Wa, Wo, W1, W2,
                                              Wv_t, Woffa_t, Wo_t, W1_t, W2_t);

    const int nElem = MROWS * D_MODEL;
    flatten_kernel<<<(nElem + 255) / 256, 256, 0, stream>>>(
        SRC[0], SRC[1], SRC[2], SRC[3], POS[0], POS[1], POS[2], POS[3],
        lemb, outbf, qbf, posbf);

    const dim3 gVA(10, 48);
    const dim3 gWo(4, 48);
    const dim3 gF1(16, 32);
    const dim3 gF2(8, 96);
    const int gMS = (MROWS * 16 + 255) / 256;
    const int gLN = MROWS / 4;

    for (int l = 0; l < NLAYERS; ++l) {
        const unsigned short* Wv_l    = Wv_t    + (size_t)l * 65536;
        const unsigned short* Woffa_l = Woffa_t + (size_t)l * 98304;
        const unsigned short* Wo_l    = Wo_t    + (size_t)l * 65536;
        const unsigned short* W1_l    = W1_t    + (size_t)l * 262144;
        const unsigned short* W2_l    = W2_t    + (size_t)l * 262144;

        pgemm_va<<<gVA, 256, 0, stream>>>(
            outbf, qbf, Wv_l, Woffa_l, bv + l * 256, boff + l * 256,
            ba + l * 128, valbf, offattn);

        msda_kernel<<<gMS, 256, 0, stream>>>(valbf, offattn, msdabf);

        // part0 = msda @ Wo + bo (bf16)
        pgemm<2, false, true><<<gWo, 256, 0, stream>>>(
            msdabf, Wo_l, bo + l * 256, part, 256);

        add_ln_kernel<1, false, false><<<gLN, 256, 0, stream>>>(
            outbf, part, g1 + l * 256, beta1 + l * 256, posbf, qbf, outf);

        pgemm<3, true, true><<<gF1, 256, 0, stream>>>(
            outbf, W1_l, bf1 + l * DFF, hbuf, 1024);

        gemm_ffn2<<<gF2, 256, 0, stream>>>(hbuf, W2_l, bf2 + l * 256, part);

        if (l < NLAYERS - 1)
            add_ln_kernel<2, true, false><<<gLN, 256, 0, stream>>>(
                outbf, part, g2 + l * 256, beta2 + l * 256, posbf, qbf, outf);
        else
            add_ln_kernel<2, false, true><<<gLN, 256, 0, stream>>>(
                outbf, part, g2 + l * 256, beta2 + l * 256, posbf, qbf, outf);
    }
}